// Round 19
// baseline (296.366 us; speedup 1.0000x reference)
//
#include <hip/hip_runtime.h>
#include <hip/hip_fp16.h>
#include <hip/hip_cooperative_groups.h>

namespace cg = cooperative_groups;

#define NN 50000
#define NE 800000
#define D  128
#define NB 391                 // node buckets of 128
#define NS 256                 // sorter blocks
#define EPS 3125               // edges per sorter (NS*EPS == NE)
#define SN (NB * NS)           // 100096 scan elements
#define SCB 1024
#define NSB ((SN + SCB - 1) / SCB)   // 98

// ---- main-path ws layout (bytes) ----
#define OFF_SLAB 0             // int2[2E]      12,800,000
#define OFF_XW   0             // ushort[NN*D]  12,800,000 (row-major; aliases dead slab)
#define OFF_CSR4 12800000      // uint[2E]       6,400,000
#define OFF_HIST 19200000      // int[SN]          400,384
#define OFF_BASE 19600384      // int[SN]          400,384
#define OFF_BSUM 20000768      // int[NSB]             512
#define OFF_ROW  20001280      // int[NN+1]        200,004
#define OFF_WF   20201344      // ushort[128*128]   32,768 (W bf16 fragments)
#define NEED_A   20234112

// ---- fallback ws layout ----
#define OFF_CNT  0
#define OFF_ROWF 200704
#define OFF_CUR  401408
#define OFF_CSR8 602112

typedef float v2f  __attribute__((ext_vector_type(2)));
typedef __attribute__((ext_vector_type(8))) short bf16x8;
typedef __attribute__((ext_vector_type(4))) float f32x4;

__device__ __forceinline__ float bf_lo(unsigned int v) { return __uint_as_float(v << 16); }
__device__ __forceinline__ float bf_hi(unsigned int v) { return __uint_as_float(v & 0xffff0000u); }
__device__ __forceinline__ float wdec(unsigned int v) {
    return __half2float(__ushort_as_half((unsigned short)(v >> 16)));
}
__device__ __forceinline__ unsigned short bf16rne(float f) {
    unsigned int b = __float_as_uint(f);
    return (unsigned short)((b + 0x7fffu + ((b >> 16) & 1u)) >> 16);
}

// ---------------------------------------------------------------------------
// Cooperative build: shist||wfrag -> scanA -> scanC -> sscat -> csr.
// 391 blocks x 256 threads; phase bodies identical to the R17-proven kernels.
// ---------------------------------------------------------------------------
__global__ __launch_bounds__(256) void gc_build(
    const int2* __restrict__ edges, const float* __restrict__ wts,
    const float* __restrict__ Wm, int* __restrict__ histT,
    int* __restrict__ bsum, int* __restrict__ baseT,
    int2* __restrict__ slab, int* __restrict__ row_start,
    unsigned int* __restrict__ csr4, unsigned short* __restrict__ wf)
{
    cg::grid_group grid = cg::this_grid();
    __shared__ int h[NB];          // shist / sscat cursors (reused)
    __shared__ int part[256];      // scans
    __shared__ int sb[128];
    __shared__ int bexc_s;
    __shared__ int ncnt[128], ncur[128];

    const int tid = threadIdx.x;
    const int bid = blockIdx.x;

    // ---- phase 1: shist (blocks 0..255)  ||  wfrag (blocks 256..319) ----
    if (bid < NS) {
        const int s = bid;
        for (int i = tid; i < NB; i += 256) h[i] = 0;
        __syncthreads();
        const int e0 = s * EPS;
        for (int i = tid; i < EPS; i += 256) {
            int2 p = edges[e0 + i];
            atomicAdd(&h[p.y >> 7], 1);
            atomicAdd(&h[p.x >> 7], 1);
        }
        __syncthreads();
        for (int b = tid; b < NB; b += 256) histT[b * NS + s] = h[b];
    } else if (bid < NS + 64) {
        int t = (bid - NS) * 256 + tid;        // 16384 total
        int j    = t & 7;
        int lane = (t >> 3) & 63;
        int nt   = (t >> 9) & 7;
        int ki   = t >> 12;
        int k = ki * 32 + (lane >> 4) * 8 + j;
        int n = nt * 16 + (lane & 15);
        wf[t] = bf16rne(Wm[k * D + n]);
    }
    grid.sync();

    // ---- phase 2: scanA (blocks 0..NSB-1) ----
    if (bid < NSB) {
        int base = bid * SCB;
        int s = 0;
        for (int i = tid; i < SCB; i += 256) {
            int idx = base + i;
            s += (idx < SN) ? histT[idx] : 0;
        }
        part[tid] = s;
        __syncthreads();
        for (int off = 128; off > 0; off >>= 1) {
            if (tid < off) part[tid] += part[tid + off];
            __syncthreads();
        }
        if (tid == 0) bsum[bid] = part[0];
    }
    grid.sync();

    // ---- phase 3: scanC (blocks 0..NSB-1), inline block-sum scan ----
    if (bid < NSB) {
        int own = 0;
        if (tid < 128) {
            own = (tid < NSB) ? bsum[tid] : 0;
            sb[tid] = own;
        }
        __syncthreads();
        for (int off = 1; off < 128; off <<= 1) {
            int v = (tid < 128 && tid >= off) ? sb[tid - off] : 0;
            __syncthreads();
            if (tid < 128) sb[tid] += v;
            __syncthreads();
        }
        if (tid == bid) bexc_s = sb[tid] - own;
        __syncthreads();

        int base = bid * SCB;
        int idx0 = base + tid * 4;
        int4 v = make_int4(0, 0, 0, 0);
        if (idx0 + 3 < SN) v = *reinterpret_cast<const int4*>(histT + idx0);
        int s = v.x + v.y + v.z + v.w;
        part[tid] = s;
        __syncthreads();
        for (int off = 1; off < 256; off <<= 1) {
            int x = (tid >= off) ? part[tid - off] : 0;
            __syncthreads();
            part[tid] += x;
            __syncthreads();
        }
        int run = bexc_s + part[tid] - s;
        if (idx0 + 3 < SN)
            *reinterpret_cast<int4*>(baseT + idx0) =
                make_int4(run, run + v.x, run + v.x + v.y, run + v.x + v.y + v.z);
    }
    grid.sync();

    // ---- phase 4: sscat (blocks 0..255) ----
    if (bid < NS) {
        const int s = bid;
        for (int b = tid; b < NB; b += 256) h[b] = baseT[b * NS + s];
        __syncthreads();
        const int e0 = s * EPS;
        for (int i = tid; i < EPS; i += 256) {
            int2 p = edges[e0 + i];
            int wb = __float_as_int(wts[e0 + i]);
            int b = p.y >> 7;
            int pos = atomicAdd(&h[b], 1);
            slab[pos] = make_int2(p.x | ((p.y & 127) << 16), wb);
            b = p.x >> 7;
            pos = atomicAdd(&h[b], 1);
            slab[pos] = make_int2(p.y | ((p.x & 127) << 16), wb);
        }
    }
    grid.sync();

    // ---- phase 5: csr (all 391 blocks) ----
    {
        const int b = bid;
        const int start = baseT[b * NS];
        const int end = (b == NB - 1) ? (2 * NE) : baseT[(b + 1) * NS];

        if (tid < 128) ncnt[tid] = 0;
        __syncthreads();

        for (int j = start + tid; j < end; j += 256)
            atomicAdd(&ncnt[(slab[j].x >> 16) & 127], 1);
        __syncthreads();

        if (tid < 128) part[tid] = ncnt[tid];
        __syncthreads();
        for (int off = 1; off < 128; off <<= 1) {
            int v = 0;
            if (tid < 128 && tid >= off) v = part[tid - off];
            __syncthreads();
            if (tid < 128) part[tid] += v;
            __syncthreads();
        }
        if (tid < 128) {
            int st = start + part[tid] - ncnt[tid];
            int n = b * 128 + tid;
            if (n < NN) row_start[n] = st;
            ncur[tid] = st;
        }
        if (b == 0 && tid == 0) row_start[NN] = 2 * NE;
        __syncthreads();

        for (int j = start + tid; j < end; j += 256) {
            int2 en = slab[j];
            int dl = (en.x >> 16) & 127;
            unsigned int hb =
                (unsigned int)__half_as_ushort(__float2half_rn(__int_as_float(en.y))) << 16;
            int pos = atomicAdd(&ncur[dl], 1);
            csr4[pos] = (unsigned int)(en.x & 0xffff) | hb;
        }
    }
}

// K5b: XW = X @ W via MFMA 16x16x32 bf16, ROW-major output (R14-proven).
__global__ __launch_bounds__(256) void gc_gemm_mfma(
    const float* __restrict__ X, const unsigned short* __restrict__ wf,
    unsigned short* __restrict__ dst)
{
    const int lane = threadIdx.x & 63;
    const int wave = threadIdx.x >> 6;
    const int rbase = blockIdx.x * 64 + wave * 16;
    const int r  = lane & 15;
    const int kb = lane >> 4;

    f32x4 acc[8];
    #pragma unroll
    for (int i = 0; i < 8; ++i) acc[i] = f32x4{0.f, 0.f, 0.f, 0.f};

    const bf16x8* wfv = reinterpret_cast<const bf16x8*>(wf);
    const int row = rbase + r;
    const bool rok = row < NN;

    #pragma unroll
    for (int ki = 0; ki < 4; ++ki) {
        float4 a0 = make_float4(0.f, 0.f, 0.f, 0.f);
        float4 a1 = make_float4(0.f, 0.f, 0.f, 0.f);
        if (rok) {
            const float4* xp = reinterpret_cast<const float4*>(
                X + (size_t)row * D + ki * 32 + kb * 8);
            a0 = xp[0];
            a1 = xp[1];
        }
        bf16x8 af;
        af[0] = (short)bf16rne(a0.x); af[1] = (short)bf16rne(a0.y);
        af[2] = (short)bf16rne(a0.z); af[3] = (short)bf16rne(a0.w);
        af[4] = (short)bf16rne(a1.x); af[5] = (short)bf16rne(a1.y);
        af[6] = (short)bf16rne(a1.z); af[7] = (short)bf16rne(a1.w);
        #pragma unroll
        for (int nt = 0; nt < 8; ++nt) {
            bf16x8 bf = wfv[(ki * 8 + nt) * 64 + lane];
            acc[nt] = __builtin_amdgcn_mfma_f32_16x16x32_bf16(af, bf, acc[nt], 0, 0, 0);
        }
    }

    const int orow0 = rbase + kb * 4;
    #pragma unroll
    for (int nt = 0; nt < 8; ++nt) {
        #pragma unroll
        for (int reg = 0; reg < 4; ++reg) {
            int orow = orow0 + reg;
            if (orow < NN)
                dst[(size_t)orow * D + nt * 16 + r] = bf16rne(acc[nt][reg]);
        }
    }
}

// K6: gather bf16 rows, wave per node, 16x unroll + 4x + scalar (R17-proven).
__global__ __launch_bounds__(256) void gc_gather4(
    const int* __restrict__ row_start, const unsigned int* __restrict__ csr4,
    const unsigned int* __restrict__ F, float* __restrict__ out)
{
    int wid  = (blockIdx.x * 256 + threadIdx.x) >> 6;
    unsigned int lane = threadIdx.x & 63;
    if (wid >= NN) return;
    int j   = row_start[wid];
    int end = row_start[wid + 1];
    v2f acc = {0.f, 0.f};
    float dw = 0.f;
    for (; j + 16 <= end; j += 16) {
        unsigned int e[16], v[16];
        #pragma unroll
        for (int q = 0; q < 16; ++q) e[q] = csr4[j + q];
        #pragma unroll
        for (int q = 0; q < 16; ++q) v[q] = F[((e[q] & 0xffffu) << 6) | lane];
        #pragma unroll
        for (int q = 0; q < 16; ++q) {
            float w = wdec(e[q]);
            acc += w * v2f{bf_lo(v[q]), bf_hi(v[q])};
            dw += w;
        }
    }
    for (; j + 4 <= end; j += 4) {
        unsigned int e0 = csr4[j],     e1 = csr4[j + 1];
        unsigned int e2 = csr4[j + 2], e3 = csr4[j + 3];
        unsigned int v0 = F[((e0 & 0xffffu) << 6) | lane];
        unsigned int v1 = F[((e1 & 0xffffu) << 6) | lane];
        unsigned int v2 = F[((e2 & 0xffffu) << 6) | lane];
        unsigned int v3 = F[((e3 & 0xffffu) << 6) | lane];
        float w0 = wdec(e0), w1 = wdec(e1), w2 = wdec(e2), w3 = wdec(e3);
        acc += w0 * v2f{bf_lo(v0), bf_hi(v0)};
        acc += w1 * v2f{bf_lo(v1), bf_hi(v1)};
        acc += w2 * v2f{bf_lo(v2), bf_hi(v2)};
        acc += w3 * v2f{bf_lo(v3), bf_hi(v3)};
        dw += (w0 + w1) + (w2 + w3);
    }
    for (; j < end; ++j) {
        unsigned int e0 = csr4[j];
        unsigned int v0 = F[((e0 & 0xffffu) << 6) | lane];
        float w0 = wdec(e0);
        acc += w0 * v2f{bf_lo(v0), bf_hi(v0)};
        dw += w0;
    }
    float inv = dw > 0.f ? 1.f / dw : 0.f;
    float2 r; r.x = acc.x * inv; r.y = acc.y * inv;
    reinterpret_cast<float2*>(out)[(size_t)wid * 64 + lane] = r;
}

// ======================= fallback path (fp32, small ws) ====================
__global__ __launch_bounds__(256) void gc_hist(
    const int2* __restrict__ edges, int* __restrict__ counts)
{
    int e = blockIdx.x * 256 + threadIdx.x;
    if (e >= NE) return;
    int2 p = edges[e];
    atomicAdd(counts + p.x, 1);
    atomicAdd(counts + p.y, 1);
}

__global__ __launch_bounds__(1024) void gc_scan(
    const int* __restrict__ counts, int* __restrict__ row_start,
    int* __restrict__ cursor)
{
    const int CHUNK = (NN + 1023) / 1024;
    __shared__ int part[1024];
    int t = threadIdx.x;
    int lo = t * CHUNK, hi = min(lo + CHUNK, NN);
    int s = 0;
    for (int i = lo; i < hi; ++i) s += counts[i];
    part[t] = s;
    __syncthreads();
    for (int off = 1; off < 1024; off <<= 1) {
        int v = (t >= off) ? part[t - off] : 0;
        __syncthreads();
        part[t] += v;
        __syncthreads();
    }
    int run = part[t] - s;
    for (int i = lo; i < hi; ++i) {
        int c = counts[i];
        row_start[i] = run;
        cursor[i]    = run;
        run += c;
    }
    if (t == 1023) row_start[NN] = part[1023];
}

__global__ __launch_bounds__(256) void gc_fill8(
    const int2* __restrict__ edges, const float* __restrict__ wts,
    int* __restrict__ cursor, int2* __restrict__ csr)
{
    int e = blockIdx.x * 256 + threadIdx.x;
    if (e >= NE) return;
    int2 p = edges[e];
    int wb = __float_as_int(wts[e]);
    int pos = atomicAdd(cursor + p.y, 1);
    csr[pos] = make_int2(p.x, wb);
    pos = atomicAdd(cursor + p.x, 1);
    csr[pos] = make_int2(p.y, wb);
}

__global__ __launch_bounds__(256) void gc_gather_f32(
    const int* __restrict__ row_start, const int2* __restrict__ csr,
    const float* __restrict__ F, float* __restrict__ out)
{
    int wid  = (blockIdx.x * 256 + threadIdx.x) >> 6;
    int lane = threadIdx.x & 63;
    if (wid >= NN) return;
    int j   = row_start[wid];
    int end = row_start[wid + 1];
    const float2* F2 = reinterpret_cast<const float2*>(F);
    float ax = 0.f, ay = 0.f, dw = 0.f;
    for (; j < end; ++j) {
        int2  cw = csr[j];
        float w  = __int_as_float(cw.y);
        float2 xv = F2[(size_t)cw.x * 64 + lane];
        ax = fmaf(w, xv.x, ax);
        ay = fmaf(w, xv.y, ay);
        dw += w;
    }
    float inv = dw > 0.f ? 1.f / dw : 0.f;
    float2 r; r.x = ax * inv; r.y = ay * inv;
    reinterpret_cast<float2*>(out)[(size_t)wid * 64 + lane] = r;
}

__global__ __launch_bounds__(256) void gc_gemm_f32(
    const float* __restrict__ src, float* __restrict__ dst,
    const float* __restrict__ Wm)
{
    __shared__ float Ws[D * D];
    __shared__ float axs[16 * D];
    const int tid = threadIdx.x;
    const int col = tid & 127;
    const int ty  = tid >> 7;
    const int rbase = blockIdx.x * 16;

    const float4* W4  = reinterpret_cast<const float4*>(Wm);
    float4*       Ws4 = reinterpret_cast<float4*>(Ws);
    #pragma unroll
    for (int i = 0; i < 16; ++i) Ws4[tid + i * 256] = W4[tid + i * 256];

    const float4* A4   = reinterpret_cast<const float4*>(src + (size_t)rbase * D);
    float4*       axs4 = reinterpret_cast<float4*>(axs);
    #pragma unroll
    for (int i = 0; i < 2; ++i) axs4[tid + i * 256] = A4[tid + i * 256];
    __syncthreads();

    float acc[8];
    #pragma unroll
    for (int i = 0; i < 8; ++i) acc[i] = 0.f;

    for (int k = 0; k < D; ++k) {
        float wv = Ws[k * D + col];
        #pragma unroll
        for (int i = 0; i < 8; ++i)
            acc[i] = fmaf(axs[(ty * 8 + i) * D + k], wv, acc[i]);
    }

    #pragma unroll
    for (int i = 0; i < 8; ++i)
        dst[(size_t)(rbase + ty * 8 + i) * D + col] = acc[i];
}

extern "C" void kernel_launch(void* const* d_in, const int* in_sizes, int n_in,
                              void* d_out, int out_size, void* d_ws, size_t ws_size,
                              hipStream_t stream) {
    const float* X     = (const float*)d_in[0];
    const int2*  edges = (const int2*)d_in[1];
    const float* wts   = (const float*)d_in[2];
    const float* Wm    = (const float*)d_in[3];
    float* out = (float*)d_out;
    char*  ws  = (char*)d_ws;

    const int eblocks = (NE + 255) / 256;

    if (ws_size >= NEED_A) {
        int2* slab  = (int2*)(ws + OFF_SLAB);
        unsigned int* csr4 = (unsigned int*)(ws + OFF_CSR4);
        int*  histT = (int*)(ws + OFF_HIST);
        int*  baseT = (int*)(ws + OFF_BASE);
        int*  bsum  = (int*)(ws + OFF_BSUM);
        int*  row   = (int*)(ws + OFF_ROW);
        unsigned short* wf = (unsigned short*)(ws + OFF_WF);
        unsigned short* xw = (unsigned short*)(ws + OFF_XW);   // aliases dead slab

        void* args[] = {
            (void*)&edges, (void*)&wts, (void*)&Wm, (void*)&histT,
            (void*)&bsum, (void*)&baseT, (void*)&slab, (void*)&row,
            (void*)&csr4, (void*)&wf
        };
        hipLaunchCooperativeKernel((void*)gc_build, dim3(NB), dim3(256),
                                   args, 0, stream);
        gc_gemm_mfma<<<(NN + 63) / 64, 256, 0, stream>>>(X, wf, xw);  // overwrites slab
        gc_gather4<<<(NN * 64 + 255) / 256, 256, 0, stream>>>(
            row, csr4, (const unsigned int*)xw, out);
    } else {
        int*  counts    = (int*) (ws + OFF_CNT);
        int*  row_start = (int*) (ws + OFF_ROWF);
        int*  cursor    = (int*) (ws + OFF_CUR);
        int2* csr       = (int2*)(ws + OFF_CSR8);

        hipMemsetAsync(counts, 0, NN * sizeof(int), stream);
        gc_hist<<<eblocks, 256, 0, stream>>>(edges, counts);
        gc_scan<<<1, 1024, 0, stream>>>(counts, row_start, cursor);
        gc_fill8<<<eblocks, 256, 0, stream>>>(edges, wts, cursor, csr);
        gc_gather_f32<<<(NN * 64 + 255) / 256, 256, 0, stream>>>(row_start, csr, X, out);
        gc_gemm_f32<<<NN / 16, 256, 0, stream>>>(out, out, Wm);
    }
}

// Round 20
// 111.997 us; speedup vs baseline: 2.6462x; 2.6462x over previous
//
#include <hip/hip_runtime.h>
#include <hip/hip_fp16.h>

#define NN 50000
#define NE 800000
#define D  128
#define NB 391                 // node buckets of 128
#define NS 256                 // sorter blocks
#define EPS 3125               // edges per sorter (NS*EPS == NE)
#define SN (NB * NS)           // 100096 scan elements
#define SCB 1024
#define NSB ((SN + SCB - 1) / SCB)   // 98

#define FLAG_PART 0x40000000u
#define FLAG_INC  0x80000000u

// ---- main-path ws layout (bytes) ----
#define OFF_SLAB 0             // int2[2E]      12,800,000
#define OFF_XW   0             // ushort[NN*D]  12,800,000 (row-major; aliases dead slab)
#define OFF_CSR4 12800000      // uint[2E]       6,400,000
#define OFF_HIST 19200000      // int[SN]          400,384
#define OFF_BASE 19600384      // int[SN]          400,384
#define OFF_DESC 20000768      // uint[NSB]            512
#define OFF_ROW  20001280      // int[NN+1]        200,004
#define OFF_WF   20201344      // ushort[128*128]   32,768 (W bf16 fragments)
#define NEED_A   20234112

// ---- fallback ws layout ----
#define OFF_CNT  0
#define OFF_ROWF 200704
#define OFF_CUR  401408
#define OFF_CSR8 602112

typedef float v2f  __attribute__((ext_vector_type(2)));
typedef __attribute__((ext_vector_type(8))) short bf16x8;
typedef __attribute__((ext_vector_type(4))) float f32x4;

__device__ __forceinline__ float bf_lo(unsigned int v) { return __uint_as_float(v << 16); }
__device__ __forceinline__ float bf_hi(unsigned int v) { return __uint_as_float(v & 0xffff0000u); }
__device__ __forceinline__ float wdec(unsigned int v) {
    return __half2float(__ushort_as_half((unsigned short)(v >> 16)));
}
__device__ __forceinline__ unsigned short bf16rne(float f) {
    unsigned int b = __float_as_uint(f);
    return (unsigned short)((b + 0x7fffu + ((b >> 16) & 1u)) >> 16);
}

// K1: shist (blocks 0..255) || wfrag (blocks 256..319) || desc init (block 320).
// Independent work sharing one dispatch; consumers are in later dispatches.
__global__ __launch_bounds__(256) void gc_shist(
    const int2* __restrict__ edges, int* __restrict__ histT,
    const float* __restrict__ Wm, unsigned short* __restrict__ wf,
    unsigned int* __restrict__ desc)
{
    const int bid = blockIdx.x;
    const int tid = threadIdx.x;
    if (bid < NS) {
        __shared__ int h[NB];
        for (int i = tid; i < NB; i += 256) h[i] = 0;
        __syncthreads();
        const int e0 = bid * EPS;
        for (int i = tid; i < EPS; i += 256) {
            int2 p = edges[e0 + i];
            atomicAdd(&h[p.y >> 7], 1);
            atomicAdd(&h[p.x >> 7], 1);
        }
        __syncthreads();
        for (int b = tid; b < NB; b += 256) histT[b * NS + bid] = h[b];
    } else if (bid < NS + 64) {
        int t = (bid - NS) * 256 + tid;        // 16384 total
        int j    = t & 7;
        int lane = (t >> 3) & 63;
        int nt   = (t >> 9) & 7;
        int ki   = t >> 12;
        int k = ki * 32 + (lane >> 4) * 8 + j;
        int n = nt * 16 + (lane & 15);
        wf[t] = bf16rne(Wm[k * D + n]);
    } else {
        if (tid < NSB) desc[tid] = 0u;         // lookback descriptors invalid
    }
}

// K2: single-pass exclusive scan with decoupled lookback. 98 blocks, all
// resident (<=256 CUs) -> spin is deadlock-free. desc word packs flag|sum
// (2E < 2^21) so a single 32-bit atomic carries both -> no fence ordering.
__global__ __launch_bounds__(256) void gc_scan1(
    const int* __restrict__ histT, unsigned int* __restrict__ desc,
    int* __restrict__ baseT)
{
    __shared__ int part[256];
    __shared__ int bexc_sh;
    const int t = threadIdx.x;
    const int b = blockIdx.x;
    int base = b * SCB;
    int idx0 = base + t * 4;
    int4 v = make_int4(0, 0, 0, 0);
    if (idx0 + 3 < SN) v = *reinterpret_cast<const int4*>(histT + idx0);
    int s = v.x + v.y + v.z + v.w;
    part[t] = s;
    __syncthreads();
    for (int off = 1; off < 256; off <<= 1) {
        int x = (t >= off) ? part[t - off] : 0;
        __syncthreads();
        part[t] += x;
        __syncthreads();
    }
    if (t == 0) {
        int agg = part[255];
        if (b == 0) {
            __hip_atomic_store(&desc[0], FLAG_INC | (unsigned)agg,
                               __ATOMIC_RELAXED, __HIP_MEMORY_SCOPE_AGENT);
            bexc_sh = 0;
        } else {
            __hip_atomic_store(&desc[b], FLAG_PART | (unsigned)agg,
                               __ATOMIC_RELAXED, __HIP_MEMORY_SCOPE_AGENT);
            int run = 0;
            int j = b - 1;
            while (true) {
                unsigned d = __hip_atomic_load(&desc[j], __ATOMIC_RELAXED,
                                               __HIP_MEMORY_SCOPE_AGENT);
                if (d == 0u) continue;
                run += (int)(d & 0x3FFFFFFFu);
                if (d & FLAG_INC) break;
                --j;
            }
            bexc_sh = run;
            __hip_atomic_store(&desc[b], FLAG_INC | (unsigned)(run + agg),
                               __ATOMIC_RELAXED, __HIP_MEMORY_SCOPE_AGENT);
        }
    }
    __syncthreads();
    int run = bexc_sh + part[t] - s;
    if (idx0 + 3 < SN)
        *reinterpret_cast<int4*>(baseT + idx0) =
            make_int4(run, run + v.x, run + v.x + v.y, run + v.x + v.y + v.z);
}

// K3: scatter entries into per-(sorter,bucket) contiguous chunks (R14-proven)
__global__ __launch_bounds__(256) void gc_sscat(
    const int2* __restrict__ edges, const float* __restrict__ wts,
    const int* __restrict__ baseT, int2* __restrict__ slab)
{
    __shared__ int cur[NB];
    const int s = blockIdx.x;
    for (int b = threadIdx.x; b < NB; b += 256) cur[b] = baseT[b * NS + s];
    __syncthreads();
    const int e0 = s * EPS;
    for (int i = threadIdx.x; i < EPS; i += 256) {
        int2 p = edges[e0 + i];
        int wb = __float_as_int(wts[e0 + i]);
        int b = p.y >> 7;
        int pos = atomicAdd(&cur[b], 1);
        slab[pos] = make_int2(p.x | ((p.y & 127) << 16), wb);
        b = p.x >> 7;
        pos = atomicAdd(&cur[b], 1);
        slab[pos] = make_int2(p.y | ((p.x & 127) << 16), wb);
    }
}

// K4: per-bucket CSR build from the contiguous bucket region (R14-proven)
__global__ __launch_bounds__(256) void gc_csr(
    const int* __restrict__ baseT, const int2* __restrict__ slab,
    int* __restrict__ row_start, unsigned int* __restrict__ csr4)
{
    __shared__ int ncnt[128], ncur[128], part[128];
    const int tid = threadIdx.x;
    const int b = blockIdx.x;
    const int start = baseT[b * NS];
    const int end = (b == NB - 1) ? (2 * NE) : baseT[(b + 1) * NS];

    if (tid < 128) ncnt[tid] = 0;
    __syncthreads();

    for (int j = start + tid; j < end; j += 256)
        atomicAdd(&ncnt[(slab[j].x >> 16) & 127], 1);
    __syncthreads();

    if (tid < 128) part[tid] = ncnt[tid];
    __syncthreads();
    for (int off = 1; off < 128; off <<= 1) {
        int v = 0;
        if (tid < 128 && tid >= off) v = part[tid - off];
        __syncthreads();
        if (tid < 128) part[tid] += v;
        __syncthreads();
    }
    if (tid < 128) {
        int st = start + part[tid] - ncnt[tid];
        int n = b * 128 + tid;
        if (n < NN) row_start[n] = st;
        ncur[tid] = st;
    }
    if (b == 0 && tid == 0) row_start[NN] = 2 * NE;
    __syncthreads();

    for (int j = start + tid; j < end; j += 256) {
        int2 en = slab[j];
        int dl = (en.x >> 16) & 127;
        unsigned int hb =
            (unsigned int)__half_as_ushort(__float2half_rn(__int_as_float(en.y))) << 16;
        int pos = atomicAdd(&ncur[dl], 1);
        csr4[pos] = (unsigned int)(en.x & 0xffff) | hb;
    }
}

// K5: XW = X @ W via MFMA 16x16x32 bf16, ROW-major output (R14-proven).
__global__ __launch_bounds__(256) void gc_gemm_mfma(
    const float* __restrict__ X, const unsigned short* __restrict__ wf,
    unsigned short* __restrict__ dst)
{
    const int lane = threadIdx.x & 63;
    const int wave = threadIdx.x >> 6;
    const int rbase = blockIdx.x * 64 + wave * 16;
    const int r  = lane & 15;
    const int kb = lane >> 4;

    f32x4 acc[8];
    #pragma unroll
    for (int i = 0; i < 8; ++i) acc[i] = f32x4{0.f, 0.f, 0.f, 0.f};

    const bf16x8* wfv = reinterpret_cast<const bf16x8*>(wf);
    const int row = rbase + r;
    const bool rok = row < NN;

    #pragma unroll
    for (int ki = 0; ki < 4; ++ki) {
        float4 a0 = make_float4(0.f, 0.f, 0.f, 0.f);
        float4 a1 = make_float4(0.f, 0.f, 0.f, 0.f);
        if (rok) {
            const float4* xp = reinterpret_cast<const float4*>(
                X + (size_t)row * D + ki * 32 + kb * 8);
            a0 = xp[0];
            a1 = xp[1];
        }
        bf16x8 af;
        af[0] = (short)bf16rne(a0.x); af[1] = (short)bf16rne(a0.y);
        af[2] = (short)bf16rne(a0.z); af[3] = (short)bf16rne(a0.w);
        af[4] = (short)bf16rne(a1.x); af[5] = (short)bf16rne(a1.y);
        af[6] = (short)bf16rne(a1.z); af[7] = (short)bf16rne(a1.w);
        #pragma unroll
        for (int nt = 0; nt < 8; ++nt) {
            bf16x8 bf = wfv[(ki * 8 + nt) * 64 + lane];
            acc[nt] = __builtin_amdgcn_mfma_f32_16x16x32_bf16(af, bf, acc[nt], 0, 0, 0);
        }
    }

    const int orow0 = rbase + kb * 4;
    #pragma unroll
    for (int nt = 0; nt < 8; ++nt) {
        #pragma unroll
        for (int reg = 0; reg < 4; ++reg) {
            int orow = orow0 + reg;
            if (orow < NN)
                dst[(size_t)orow * D + nt * 16 + r] = bf16rne(acc[nt][reg]);
        }
    }
}

// K6: gather bf16 rows, wave per node, 16x unroll + 4x + scalar (R17-proven).
__global__ __launch_bounds__(256) void gc_gather4(
    const int* __restrict__ row_start, const unsigned int* __restrict__ csr4,
    const unsigned int* __restrict__ F, float* __restrict__ out)
{
    int wid  = (blockIdx.x * 256 + threadIdx.x) >> 6;
    unsigned int lane = threadIdx.x & 63;
    if (wid >= NN) return;
    int j   = row_start[wid];
    int end = row_start[wid + 1];
    v2f acc = {0.f, 0.f};
    float dw = 0.f;
    for (; j + 16 <= end; j += 16) {
        unsigned int e[16], v[16];
        #pragma unroll
        for (int q = 0; q < 16; ++q) e[q] = csr4[j + q];
        #pragma unroll
        for (int q = 0; q < 16; ++q) v[q] = F[((e[q] & 0xffffu) << 6) | lane];
        #pragma unroll
        for (int q = 0; q < 16; ++q) {
            float w = wdec(e[q]);
            acc += w * v2f{bf_lo(v[q]), bf_hi(v[q])};
            dw += w;
        }
    }
    for (; j + 4 <= end; j += 4) {
        unsigned int e0 = csr4[j],     e1 = csr4[j + 1];
        unsigned int e2 = csr4[j + 2], e3 = csr4[j + 3];
        unsigned int v0 = F[((e0 & 0xffffu) << 6) | lane];
        unsigned int v1 = F[((e1 & 0xffffu) << 6) | lane];
        unsigned int v2 = F[((e2 & 0xffffu) << 6) | lane];
        unsigned int v3 = F[((e3 & 0xffffu) << 6) | lane];
        float w0 = wdec(e0), w1 = wdec(e1), w2 = wdec(e2), w3 = wdec(e3);
        acc += w0 * v2f{bf_lo(v0), bf_hi(v0)};
        acc += w1 * v2f{bf_lo(v1), bf_hi(v1)};
        acc += w2 * v2f{bf_lo(v2), bf_hi(v2)};
        acc += w3 * v2f{bf_lo(v3), bf_hi(v3)};
        dw += (w0 + w1) + (w2 + w3);
    }
    for (; j < end; ++j) {
        unsigned int e0 = csr4[j];
        unsigned int v0 = F[((e0 & 0xffffu) << 6) | lane];
        float w0 = wdec(e0);
        acc += w0 * v2f{bf_lo(v0), bf_hi(v0)};
        dw += w0;
    }
    float inv = dw > 0.f ? 1.f / dw : 0.f;
    float2 r; r.x = acc.x * inv; r.y = acc.y * inv;
    reinterpret_cast<float2*>(out)[(size_t)wid * 64 + lane] = r;
}

// ======================= fallback path (fp32, small ws) ====================
__global__ __launch_bounds__(256) void gc_hist(
    const int2* __restrict__ edges, int* __restrict__ counts)
{
    int e = blockIdx.x * 256 + threadIdx.x;
    if (e >= NE) return;
    int2 p = edges[e];
    atomicAdd(counts + p.x, 1);
    atomicAdd(counts + p.y, 1);
}

__global__ __launch_bounds__(1024) void gc_scan(
    const int* __restrict__ counts, int* __restrict__ row_start,
    int* __restrict__ cursor)
{
    const int CHUNK = (NN + 1023) / 1024;
    __shared__ int part[1024];
    int t = threadIdx.x;
    int lo = t * CHUNK, hi = min(lo + CHUNK, NN);
    int s = 0;
    for (int i = lo; i < hi; ++i) s += counts[i];
    part[t] = s;
    __syncthreads();
    for (int off = 1; off < 1024; off <<= 1) {
        int v = (t >= off) ? part[t - off] : 0;
        __syncthreads();
        part[t] += v;
        __syncthreads();
    }
    int run = part[t] - s;
    for (int i = lo; i < hi; ++i) {
        int c = counts[i];
        row_start[i] = run;
        cursor[i]    = run;
        run += c;
    }
    if (t == 1023) row_start[NN] = part[1023];
}

__global__ __launch_bounds__(256) void gc_fill8(
    const int2* __restrict__ edges, const float* __restrict__ wts,
    int* __restrict__ cursor, int2* __restrict__ csr)
{
    int e = blockIdx.x * 256 + threadIdx.x;
    if (e >= NE) return;
    int2 p = edges[e];
    int wb = __float_as_int(wts[e]);
    int pos = atomicAdd(cursor + p.y, 1);
    csr[pos] = make_int2(p.x, wb);
    pos = atomicAdd(cursor + p.x, 1);
    csr[pos] = make_int2(p.y, wb);
}

__global__ __launch_bounds__(256) void gc_gather_f32(
    const int* __restrict__ row_start, const int2* __restrict__ csr,
    const float* __restrict__ F, float* __restrict__ out)
{
    int wid  = (blockIdx.x * 256 + threadIdx.x) >> 6;
    int lane = threadIdx.x & 63;
    if (wid >= NN) return;
    int j   = row_start[wid];
    int end = row_start[wid + 1];
    const float2* F2 = reinterpret_cast<const float2*>(F);
    float ax = 0.f, ay = 0.f, dw = 0.f;
    for (; j < end; ++j) {
        int2  cw = csr[j];
        float w  = __int_as_float(cw.y);
        float2 xv = F2[(size_t)cw.x * 64 + lane];
        ax = fmaf(w, xv.x, ax);
        ay = fmaf(w, xv.y, ay);
        dw += w;
    }
    float inv = dw > 0.f ? 1.f / dw : 0.f;
    float2 r; r.x = ax * inv; r.y = ay * inv;
    reinterpret_cast<float2*>(out)[(size_t)wid * 64 + lane] = r;
}

__global__ __launch_bounds__(256) void gc_gemm_f32(
    const float* __restrict__ src, float* __restrict__ dst,
    const float* __restrict__ Wm)
{
    __shared__ float Ws[D * D];
    __shared__ float axs[16 * D];
    const int tid = threadIdx.x;
    const int col = tid & 127;
    const int ty  = tid >> 7;
    const int rbase = blockIdx.x * 16;

    const float4* W4  = reinterpret_cast<const float4*>(Wm);
    float4*       Ws4 = reinterpret_cast<float4*>(Ws);
    #pragma unroll
    for (int i = 0; i < 16; ++i) Ws4[tid + i * 256] = W4[tid + i * 256];

    const float4* A4   = reinterpret_cast<const float4*>(src + (size_t)rbase * D);
    float4*       axs4 = reinterpret_cast<float4*>(axs);
    #pragma unroll
    for (int i = 0; i < 2; ++i) axs4[tid + i * 256] = A4[tid + i * 256];
    __syncthreads();

    float acc[8];
    #pragma unroll
    for (int i = 0; i < 8; ++i) acc[i] = 0.f;

    for (int k = 0; k < D; ++k) {
        float wv = Ws[k * D + col];
        #pragma unroll
        for (int i = 0; i < 8; ++i)
            acc[i] = fmaf(axs[(ty * 8 + i) * D + k], wv, acc[i]);
    }

    #pragma unroll
    for (int i = 0; i < 8; ++i)
        dst[(size_t)(rbase + ty * 8 + i) * D + col] = acc[i];
}

extern "C" void kernel_launch(void* const* d_in, const int* in_sizes, int n_in,
                              void* d_out, int out_size, void* d_ws, size_t ws_size,
                              hipStream_t stream) {
    const float* X     = (const float*)d_in[0];
    const int2*  edges = (const int2*)d_in[1];
    const float* wts   = (const float*)d_in[2];
    const float* Wm    = (const float*)d_in[3];
    float* out = (float*)d_out;
    char*  ws  = (char*)d_ws;

    const int eblocks = (NE + 255) / 256;

    if (ws_size >= NEED_A) {
        int2* slab  = (int2*)(ws + OFF_SLAB);
        unsigned int* csr4 = (unsigned int*)(ws + OFF_CSR4);
        int*  histT = (int*)(ws + OFF_HIST);
        int*  baseT = (int*)(ws + OFF_BASE);
        unsigned int* desc = (unsigned int*)(ws + OFF_DESC);
        int*  row   = (int*)(ws + OFF_ROW);
        unsigned short* wf = (unsigned short*)(ws + OFF_WF);
        unsigned short* xw = (unsigned short*)(ws + OFF_XW);   // aliases dead slab

        gc_shist<<<NS + 64 + 1, 256, 0, stream>>>(edges, histT, Wm, wf, desc);
        gc_scan1<<<NSB, 256, 0, stream>>>(histT, desc, baseT);
        gc_sscat<<<NS, 256, 0, stream>>>(edges, wts, baseT, slab);
        gc_csr<<<NB, 256, 0, stream>>>(baseT, slab, row, csr4);
        gc_gemm_mfma<<<(NN + 63) / 64, 256, 0, stream>>>(X, wf, xw);  // overwrites slab
        gc_gather4<<<(NN * 64 + 255) / 256, 256, 0, stream>>>(
            row, csr4, (const unsigned int*)xw, out);
    } else {
        int*  counts    = (int*) (ws + OFF_CNT);
        int*  row_start = (int*) (ws + OFF_ROWF);
        int*  cursor    = (int*) (ws + OFF_CUR);
        int2* csr       = (int2*)(ws + OFF_CSR8);

        hipMemsetAsync(counts, 0, NN * sizeof(int), stream);
        gc_hist<<<eblocks, 256, 0, stream>>>(edges, counts);
        gc_scan<<<1, 1024, 0, stream>>>(counts, row_start, cursor);
        gc_fill8<<<eblocks, 256, 0, stream>>>(edges, wts, cursor, csr);
        gc_gather_f32<<<(NN * 64 + 255) / 256, 256, 0, stream>>>(row_start, csr, X, out);
        gc_gemm_f32<<<NN / 16, 256, 0, stream>>>(out, out, Wm);
    }
}

// Round 21
// 102.049 us; speedup vs baseline: 2.9042x; 1.0975x over previous
//
#include <hip/hip_runtime.h>
#include <hip/hip_fp16.h>

#define NN 50000
#define NE 800000
#define D  128
#define NB 391                 // node buckets of 128
#define NS 256                 // sorter blocks
#define EPS 3125               // edges per sorter (NS*EPS == NE)
#define SN (NB * NS)           // 100096 scan elements
#define SCB 1024
#define NSB ((SN + SCB - 1) / SCB)   // 98
#define GEMMB ((NN + 63) / 64)       // 782 gemm blocks

// ---- main-path ws layout (bytes). XW un-aliased so gemm can overlap build.
#define OFF_SLAB 0             // int2[2E]      12,800,000
#define OFF_CSR4 12800000      // uint[2E]       6,400,000
#define OFF_HIST 19200000      // int[SN]          400,384
#define OFF_BASE 19600384      // int[SN]          400,384
#define OFF_BSUM 20000768      // int[NSB]             512
#define OFF_ROW  20001280      // int[NN+1]        200,004
#define OFF_WF   20201344      // ushort[128*128]   32,768
#define OFF_XW   20234112      // ushort[NN*D]  12,800,000 (own region)
#define NEED_A   33034112

// ---- fallback ws layout ----
#define OFF_CNT  0
#define OFF_ROWF 200704
#define OFF_CUR  401408
#define OFF_CSR8 602112

typedef float v2f  __attribute__((ext_vector_type(2)));
typedef __attribute__((ext_vector_type(8))) short bf16x8;
typedef __attribute__((ext_vector_type(4))) float f32x4;

__device__ __forceinline__ float bf_lo(unsigned int v) { return __uint_as_float(v << 16); }
__device__ __forceinline__ float bf_hi(unsigned int v) { return __uint_as_float(v & 0xffff0000u); }
__device__ __forceinline__ float wdec(unsigned int v) {
    return __half2float(__ushort_as_half((unsigned short)(v >> 16)));
}
__device__ __forceinline__ unsigned short bf16rne(float f) {
    unsigned int b = __float_as_uint(f);
    return (unsigned short)((b + 0x7fffu + ((b >> 16) & 1u)) >> 16);
}

// K1: shist (blocks 0..255) || wfrag (blocks 256..319).
__global__ __launch_bounds__(256) void gc_shist(
    const int2* __restrict__ edges, int* __restrict__ histT,
    const float* __restrict__ Wm, unsigned short* __restrict__ wf)
{
    const int bid = blockIdx.x;
    const int tid = threadIdx.x;
    if (bid < NS) {
        __shared__ int h[NB];
        for (int i = tid; i < NB; i += 256) h[i] = 0;
        __syncthreads();
        const int e0 = bid * EPS;
        for (int i = tid; i < EPS; i += 256) {
            int2 p = edges[e0 + i];
            atomicAdd(&h[p.y >> 7], 1);
            atomicAdd(&h[p.x >> 7], 1);
        }
        __syncthreads();
        for (int b = tid; b < NB; b += 256) histT[b * NS + bid] = h[b];
    } else if (bid < NS + 64) {
        int t = (bid - NS) * 256 + tid;        // 16384 total
        int j    = t & 7;
        int lane = (t >> 3) & 63;
        int nt   = (t >> 9) & 7;
        int ki   = t >> 12;
        int k = ki * 32 + (lane >> 4) * 8 + j;
        int n = nt * 16 + (lane & 15);
        wf[t] = bf16rne(Wm[k * D + n]);
    }
}

// K2a: per-chunk partial sums (R17-proven)
__global__ __launch_bounds__(256) void gc_scanA(
    const int* __restrict__ in, int* __restrict__ bsum)
{
    __shared__ int red[256];
    int base = blockIdx.x * SCB;
    int s = 0;
    for (int i = threadIdx.x; i < SCB; i += 256) {
        int idx = base + i;
        s += (idx < SN) ? in[idx] : 0;
    }
    red[threadIdx.x] = s;
    __syncthreads();
    for (int off = 128; off > 0; off >>= 1) {
        if (threadIdx.x < off) red[threadIdx.x] += red[threadIdx.x + off];
        __syncthreads();
    }
    if (threadIdx.x == 0) bsum[blockIdx.x] = red[0];
}

// K2b: per-chunk local scan + inline scan of the 98 block sums (R17-proven)
__global__ __launch_bounds__(256) void gc_scanC(
    const int* __restrict__ in, const int* __restrict__ bsum,
    int* __restrict__ baseT)
{
    __shared__ int part[256];
    __shared__ int sb[128];
    __shared__ int bexc;
    const int t = threadIdx.x;

    int own = 0;
    if (t < 128) {
        own = (t < NSB) ? bsum[t] : 0;
        sb[t] = own;
    }
    __syncthreads();
    for (int off = 1; off < 128; off <<= 1) {
        int v = (t < 128 && t >= off) ? sb[t - off] : 0;
        __syncthreads();
        if (t < 128) sb[t] += v;
        __syncthreads();
    }
    if (t == (int)blockIdx.x) bexc = sb[t] - own;
    __syncthreads();

    int base = blockIdx.x * SCB;
    int idx0 = base + t * 4;
    int4 v = make_int4(0, 0, 0, 0);
    if (idx0 + 3 < SN) v = *reinterpret_cast<const int4*>(in + idx0);
    int s = v.x + v.y + v.z + v.w;
    part[t] = s;
    __syncthreads();
    for (int off = 1; off < 256; off <<= 1) {
        int x = (t >= off) ? part[t - off] : 0;
        __syncthreads();
        part[t] += x;
        __syncthreads();
    }
    int run = bexc + part[t] - s;
    if (idx0 + 3 < SN)
        *reinterpret_cast<int4*>(baseT + idx0) =
            make_int4(run, run + v.x, run + v.x + v.y, run + v.x + v.y + v.z);
}

// K3: FUSED sscat (blocks 0..255) || gemm_mfma (blocks 256..1037).
// Independent work: sscat writes slab from baseT; gemm writes XW (own region)
// from X and wf. Consumers (csr, gather) are in later dispatches.
__global__ __launch_bounds__(256) void gc_sscat_gemm(
    const int2* __restrict__ edges, const float* __restrict__ wts,
    const int* __restrict__ baseT, int2* __restrict__ slab,
    const float* __restrict__ X, const unsigned short* __restrict__ wf,
    unsigned short* __restrict__ xw)
{
    const int bid = blockIdx.x;
    const int tid = threadIdx.x;
    if (bid < NS) {
        __shared__ int cur[NB];
        const int s = bid;
        for (int b = tid; b < NB; b += 256) cur[b] = baseT[b * NS + s];
        __syncthreads();
        const int e0 = s * EPS;
        for (int i = tid; i < EPS; i += 256) {
            int2 p = edges[e0 + i];
            int wb = __float_as_int(wts[e0 + i]);
            int b = p.y >> 7;
            int pos = atomicAdd(&cur[b], 1);
            slab[pos] = make_int2(p.x | ((p.y & 127) << 16), wb);
            b = p.x >> 7;
            pos = atomicAdd(&cur[b], 1);
            slab[pos] = make_int2(p.y | ((p.x & 127) << 16), wb);
        }
    } else {
        const int gb   = bid - NS;             // 0..GEMMB-1
        const int lane = tid & 63;
        const int wave = tid >> 6;
        const int rbase = gb * 64 + wave * 16;
        const int r  = lane & 15;
        const int kb = lane >> 4;

        f32x4 acc[8];
        #pragma unroll
        for (int i = 0; i < 8; ++i) acc[i] = f32x4{0.f, 0.f, 0.f, 0.f};

        const bf16x8* wfv = reinterpret_cast<const bf16x8*>(wf);
        const int row = rbase + r;
        const bool rok = row < NN;

        #pragma unroll
        for (int ki = 0; ki < 4; ++ki) {
            float4 a0 = make_float4(0.f, 0.f, 0.f, 0.f);
            float4 a1 = make_float4(0.f, 0.f, 0.f, 0.f);
            if (rok) {
                const float4* xp = reinterpret_cast<const float4*>(
                    X + (size_t)row * D + ki * 32 + kb * 8);
                a0 = xp[0];
                a1 = xp[1];
            }
            bf16x8 af;
            af[0] = (short)bf16rne(a0.x); af[1] = (short)bf16rne(a0.y);
            af[2] = (short)bf16rne(a0.z); af[3] = (short)bf16rne(a0.w);
            af[4] = (short)bf16rne(a1.x); af[5] = (short)bf16rne(a1.y);
            af[6] = (short)bf16rne(a1.z); af[7] = (short)bf16rne(a1.w);
            #pragma unroll
            for (int nt = 0; nt < 8; ++nt) {
                bf16x8 bf = wfv[(ki * 8 + nt) * 64 + lane];
                acc[nt] = __builtin_amdgcn_mfma_f32_16x16x32_bf16(af, bf, acc[nt], 0, 0, 0);
            }
        }

        const int orow0 = rbase + kb * 4;
        #pragma unroll
        for (int nt = 0; nt < 8; ++nt) {
            #pragma unroll
            for (int reg = 0; reg < 4; ++reg) {
                int orow = orow0 + reg;
                if (orow < NN)
                    xw[(size_t)orow * D + nt * 16 + r] = bf16rne(acc[nt][reg]);
            }
        }
    }
}

// K4: per-bucket CSR build from the contiguous bucket region (R14-proven)
__global__ __launch_bounds__(256) void gc_csr(
    const int* __restrict__ baseT, const int2* __restrict__ slab,
    int* __restrict__ row_start, unsigned int* __restrict__ csr4)
{
    __shared__ int ncnt[128], ncur[128], part[128];
    const int tid = threadIdx.x;
    const int b = blockIdx.x;
    const int start = baseT[b * NS];
    const int end = (b == NB - 1) ? (2 * NE) : baseT[(b + 1) * NS];

    if (tid < 128) ncnt[tid] = 0;
    __syncthreads();

    for (int j = start + tid; j < end; j += 256)
        atomicAdd(&ncnt[(slab[j].x >> 16) & 127], 1);
    __syncthreads();

    if (tid < 128) part[tid] = ncnt[tid];
    __syncthreads();
    for (int off = 1; off < 128; off <<= 1) {
        int v = 0;
        if (tid < 128 && tid >= off) v = part[tid - off];
        __syncthreads();
        if (tid < 128) part[tid] += v;
        __syncthreads();
    }
    if (tid < 128) {
        int st = start + part[tid] - ncnt[tid];
        int n = b * 128 + tid;
        if (n < NN) row_start[n] = st;
        ncur[tid] = st;
    }
    if (b == 0 && tid == 0) row_start[NN] = 2 * NE;
    __syncthreads();

    for (int j = start + tid; j < end; j += 256) {
        int2 en = slab[j];
        int dl = (en.x >> 16) & 127;
        unsigned int hb =
            (unsigned int)__half_as_ushort(__float2half_rn(__int_as_float(en.y))) << 16;
        int pos = atomicAdd(&ncur[dl], 1);
        csr4[pos] = (unsigned int)(en.x & 0xffff) | hb;
    }
}

// K5: gather bf16 rows, wave per node, 16x unroll + 4x + scalar (R17-proven).
__global__ __launch_bounds__(256) void gc_gather4(
    const int* __restrict__ row_start, const unsigned int* __restrict__ csr4,
    const unsigned int* __restrict__ F, float* __restrict__ out)
{
    int wid  = (blockIdx.x * 256 + threadIdx.x) >> 6;
    unsigned int lane = threadIdx.x & 63;
    if (wid >= NN) return;
    int j   = row_start[wid];
    int end = row_start[wid + 1];
    v2f acc = {0.f, 0.f};
    float dw = 0.f;
    for (; j + 16 <= end; j += 16) {
        unsigned int e[16], v[16];
        #pragma unroll
        for (int q = 0; q < 16; ++q) e[q] = csr4[j + q];
        #pragma unroll
        for (int q = 0; q < 16; ++q) v[q] = F[((e[q] & 0xffffu) << 6) | lane];
        #pragma unroll
        for (int q = 0; q < 16; ++q) {
            float w = wdec(e[q]);
            acc += w * v2f{bf_lo(v[q]), bf_hi(v[q])};
            dw += w;
        }
    }
    for (; j + 4 <= end; j += 4) {
        unsigned int e0 = csr4[j],     e1 = csr4[j + 1];
        unsigned int e2 = csr4[j + 2], e3 = csr4[j + 3];
        unsigned int v0 = F[((e0 & 0xffffu) << 6) | lane];
        unsigned int v1 = F[((e1 & 0xffffu) << 6) | lane];
        unsigned int v2 = F[((e2 & 0xffffu) << 6) | lane];
        unsigned int v3 = F[((e3 & 0xffffu) << 6) | lane];
        float w0 = wdec(e0), w1 = wdec(e1), w2 = wdec(e2), w3 = wdec(e3);
        acc += w0 * v2f{bf_lo(v0), bf_hi(v0)};
        acc += w1 * v2f{bf_lo(v1), bf_hi(v1)};
        acc += w2 * v2f{bf_lo(v2), bf_hi(v2)};
        acc += w3 * v2f{bf_lo(v3), bf_hi(v3)};
        dw += (w0 + w1) + (w2 + w3);
    }
    for (; j < end; ++j) {
        unsigned int e0 = csr4[j];
        unsigned int v0 = F[((e0 & 0xffffu) << 6) | lane];
        float w0 = wdec(e0);
        acc += w0 * v2f{bf_lo(v0), bf_hi(v0)};
        dw += w0;
    }
    float inv = dw > 0.f ? 1.f / dw : 0.f;
    float2 r; r.x = acc.x * inv; r.y = acc.y * inv;
    reinterpret_cast<float2*>(out)[(size_t)wid * 64 + lane] = r;
}

// ======================= fallback path (fp32, small ws) ====================
__global__ __launch_bounds__(256) void gc_hist(
    const int2* __restrict__ edges, int* __restrict__ counts)
{
    int e = blockIdx.x * 256 + threadIdx.x;
    if (e >= NE) return;
    int2 p = edges[e];
    atomicAdd(counts + p.x, 1);
    atomicAdd(counts + p.y, 1);
}

__global__ __launch_bounds__(1024) void gc_scan(
    const int* __restrict__ counts, int* __restrict__ row_start,
    int* __restrict__ cursor)
{
    const int CHUNK = (NN + 1023) / 1024;
    __shared__ int part[1024];
    int t = threadIdx.x;
    int lo = t * CHUNK, hi = min(lo + CHUNK, NN);
    int s = 0;
    for (int i = lo; i < hi; ++i) s += counts[i];
    part[t] = s;
    __syncthreads();
    for (int off = 1; off < 1024; off <<= 1) {
        int v = (t >= off) ? part[t - off] : 0;
        __syncthreads();
        part[t] += v;
        __syncthreads();
    }
    int run = part[t] - s;
    for (int i = lo; i < hi; ++i) {
        int c = counts[i];
        row_start[i] = run;
        cursor[i]    = run;
        run += c;
    }
    if (t == 1023) row_start[NN] = part[1023];
}

__global__ __launch_bounds__(256) void gc_fill8(
    const int2* __restrict__ edges, const float* __restrict__ wts,
    int* __restrict__ cursor, int2* __restrict__ csr)
{
    int e = blockIdx.x * 256 + threadIdx.x;
    if (e >= NE) return;
    int2 p = edges[e];
    int wb = __float_as_int(wts[e]);
    int pos = atomicAdd(cursor + p.y, 1);
    csr[pos] = make_int2(p.x, wb);
    pos = atomicAdd(cursor + p.x, 1);
    csr[pos] = make_int2(p.y, wb);
}

__global__ __launch_bounds__(256) void gc_gather_f32(
    const int* __restrict__ row_start, const int2* __restrict__ csr,
    const float* __restrict__ F, float* __restrict__ out)
{
    int wid  = (blockIdx.x * 256 + threadIdx.x) >> 6;
    int lane = threadIdx.x & 63;
    if (wid >= NN) return;
    int j   = row_start[wid];
    int end = row_start[wid + 1];
    const float2* F2 = reinterpret_cast<const float2*>(F);
    float ax = 0.f, ay = 0.f, dw = 0.f;
    for (; j < end; ++j) {
        int2  cw = csr[j];
        float w  = __int_as_float(cw.y);
        float2 xv = F2[(size_t)cw.x * 64 + lane];
        ax = fmaf(w, xv.x, ax);
        ay = fmaf(w, xv.y, ay);
        dw += w;
    }
    float inv = dw > 0.f ? 1.f / dw : 0.f;
    float2 r; r.x = ax * inv; r.y = ay * inv;
    reinterpret_cast<float2*>(out)[(size_t)wid * 64 + lane] = r;
}

__global__ __launch_bounds__(256) void gc_gemm_f32(
    const float* __restrict__ src, float* __restrict__ dst,
    const float* __restrict__ Wm)
{
    __shared__ float Ws[D * D];
    __shared__ float axs[16 * D];
    const int tid = threadIdx.x;
    const int col = tid & 127;
    const int ty  = tid >> 7;
    const int rbase = blockIdx.x * 16;

    const float4* W4  = reinterpret_cast<const float4*>(Wm);
    float4*       Ws4 = reinterpret_cast<float4*>(Ws);
    #pragma unroll
    for (int i = 0; i < 16; ++i) Ws4[tid + i * 256] = W4[tid + i * 256];

    const float4* A4   = reinterpret_cast<const float4*>(src + (size_t)rbase * D);
    float4*       axs4 = reinterpret_cast<float4*>(axs);
    #pragma unroll
    for (int i = 0; i < 2; ++i) axs4[tid + i * 256] = A4[tid + i * 256];
    __syncthreads();

    float acc[8];
    #pragma unroll
    for (int i = 0; i < 8; ++i) acc[i] = 0.f;

    for (int k = 0; k < D; ++k) {
        float wv = Ws[k * D + col];
        #pragma unroll
        for (int i = 0; i < 8; ++i)
            acc[i] = fmaf(axs[(ty * 8 + i) * D + k], wv, acc[i]);
    }

    #pragma unroll
    for (int i = 0; i < 8; ++i)
        dst[(size_t)(rbase + ty * 8 + i) * D + col] = acc[i];
}

extern "C" void kernel_launch(void* const* d_in, const int* in_sizes, int n_in,
                              void* d_out, int out_size, void* d_ws, size_t ws_size,
                              hipStream_t stream) {
    const float* X     = (const float*)d_in[0];
    const int2*  edges = (const int2*)d_in[1];
    const float* wts   = (const float*)d_in[2];
    const float* Wm    = (const float*)d_in[3];
    float* out = (float*)d_out;
    char*  ws  = (char*)d_ws;

    const int eblocks = (NE + 255) / 256;

    if (ws_size >= NEED_A) {
        int2* slab  = (int2*)(ws + OFF_SLAB);
        unsigned int* csr4 = (unsigned int*)(ws + OFF_CSR4);
        int*  histT = (int*)(ws + OFF_HIST);
        int*  baseT = (int*)(ws + OFF_BASE);
        int*  bsum  = (int*)(ws + OFF_BSUM);
        int*  row   = (int*)(ws + OFF_ROW);
        unsigned short* wf = (unsigned short*)(ws + OFF_WF);
        unsigned short* xw = (unsigned short*)(ws + OFF_XW);

        gc_shist<<<NS + 64, 256, 0, stream>>>(edges, histT, Wm, wf);
        gc_scanA<<<NSB, 256, 0, stream>>>(histT, bsum);
        gc_scanC<<<NSB, 256, 0, stream>>>(histT, bsum, baseT);
        gc_sscat_gemm<<<NS + GEMMB, 256, 0, stream>>>(
            edges, wts, baseT, slab, X, wf, xw);
        gc_csr<<<NB, 256, 0, stream>>>(baseT, slab, row, csr4);
        gc_gather4<<<(NN * 64 + 255) / 256, 256, 0, stream>>>(
            row, csr4, (const unsigned int*)xw, out);
    } else {
        int*  counts    = (int*) (ws + OFF_CNT);
        int*  row_start = (int*) (ws + OFF_ROWF);
        int*  cursor    = (int*) (ws + OFF_CUR);
        int2* csr       = (int2*)(ws + OFF_CSR8);

        hipMemsetAsync(counts, 0, NN * sizeof(int), stream);
        gc_hist<<<eblocks, 256, 0, stream>>>(edges, counts);
        gc_scan<<<1, 1024, 0, stream>>>(counts, row_start, cursor);
        gc_fill8<<<eblocks, 256, 0, stream>>>(edges, wts, cursor, csr);
        gc_gather_f32<<<(NN * 64 + 255) / 256, 256, 0, stream>>>(row_start, csr, X, out);
        gc_gemm_f32<<<NN / 16, 256, 0, stream>>>(out, out, Wm);
    }
}